// Round 1
// baseline (284.216 us; speedup 1.0000x reference)
//
#include <hip/hip_runtime.h>
#include <cmath>

// Problem constants (from reference)
constexpr int Bn = 32, An = 3, Sn = 80, NCc = 80;
constexpr int NCELL = Bn * An * Sn * Sn;     // 614400
constexpr int BDIM  = 256;
constexpr int NBLK  = NCELL / BDIM;          // 2400 (exact)
constexpr float EPSc = 1e-7f;

__device__ __forceinline__ float bce_logits(float z, float t) {
    // max(z,0) - z*t + log1p(exp(-|z|))
    return fmaxf(z, 0.f) - z * t + log1pf(expf(-fabsf(z)));
}

__global__ __launch_bounds__(BDIM) void yolo_main(
    const float* __restrict__ pred, const float* __restrict__ target,
    const float* __restrict__ anchors, float* __restrict__ partials)
{
    const int i    = blockIdx.x * BDIM + threadIdx.x;   // one thread per cell
    const int lane = threadIdx.x & 63;

    const float* tt = target + (size_t)i * 6;
    const float* pp = pred   + (size_t)i * 85;

    const float t0 = tt[0];
    const float z0 = pp[0];
    const bool obj   = (t0 == 1.0f);
    const bool noobj = (t0 == 0.0f);

    float nsum = 0.f, ncnt = 0.f, bsum = 0.f, osum = 0.f, csum = 0.f, ocnt = 0.f;

    if (noobj) {
        nsum = bce_logits(z0, t0);
        ncnt = 1.f;
    }

    if (obj) {
        // ---- box decode + CIoU (per-lane, exec-masked; ~3/64 lanes active) ----
        const float p1 = pp[1], p2 = pp[2], p3 = pp[3], p4 = pp[4];
        const float px = 1.f / (1.f + expf(-p1));
        const float py = 1.f / (1.f + expf(-p2));
        const int   a  = (i / (Sn * Sn)) % An;
        const float pw = expf(p3) * anchors[2 * a];
        const float ph = expf(p4) * anchors[2 * a + 1];
        const float tx = tt[1], ty = tt[2], tw = tt[3], th = tt[4];

        const float x1a = px - pw * 0.5f, x1b = px + pw * 0.5f;
        const float y1a = py - ph * 0.5f, y1b = py + ph * 0.5f;
        const float x2a = tx - tw * 0.5f, x2b = tx + tw * 0.5f;
        const float y2a = ty - th * 0.5f, y2b = ty + th * 0.5f;

        const float iw = fmaxf(fminf(x1b, x2b) - fmaxf(x1a, x2a), 0.f);
        const float ih = fmaxf(fminf(y1b, y2b) - fmaxf(y1a, y2a), 0.f);
        const float inter = iw * ih;
        const float uni   = pw * ph + tw * th - inter + EPSc;
        const float iou   = inter / uni;

        const float cw = fmaxf(x1b, x2b) - fminf(x1a, x2a);
        const float ch = fmaxf(y1b, y2b) - fminf(y1a, y2a);
        const float c2 = cw * cw + ch * ch + EPSc;
        const float rho2 = (tx - px) * (tx - px) + (ty - py) * (ty - py);

        const float fopi2 = 4.0f / (3.14159265358979323846f * 3.14159265358979323846f);
        const float dv = atanf(tw / (th + EPSc)) - atanf(pw / (ph + EPSc));
        const float v  = fopi2 * dv * dv;
        const float alpha = v / (1.f - iou + v + EPSc);
        const float ciou  = iou - rho2 / c2 - alpha * v;

        bsum = 1.f - ciou;

        // object loss: BCE-with-logits applied to sigmoid(z0) (reference quirk)
        const float s0 = 1.f / (1.f + expf(-z0));
        osum = bce_logits(s0, t0);
        ocnt = 1.f;
    }

    // ---- class loss: wave-cooperative softmax per obj cell ----
    unsigned long long mask = __ballot(obj);
    const int wave_base = i - lane;
    while (mask) {
        const int lj = __builtin_ctzll(mask);
        mask &= mask - 1;
        const int cj = wave_base + lj;

        const float* pc = pred + (size_t)cj * 85 + 5;
        const float z1 = pc[lane];                                  // classes 0..63
        const float z2 = (lane < NCc - 64) ? pc[64 + lane] : -INFINITY; // 64..79

        float m = fmaxf(z1, z2);
        #pragma unroll
        for (int off = 32; off; off >>= 1) m = fmaxf(m, __shfl_xor(m, off));

        float e  = expf(z1 - m) + ((lane < NCc - 64) ? expf(z2 - m) : 0.f);
        float sz = z1 + ((lane < NCc - 64) ? z2 : 0.f);
        #pragma unroll
        for (int off = 32; off; off >>= 1) {
            e  += __shfl_xor(e, off);
            sz += __shfl_xor(sz, off);
        }
        const float lse = m + logf(e);

        const int k = (int)target[(size_t)cj * 6 + 5];   // uniform (same addr all lanes)
        const float zk = (k < 64) ? __shfl(z1, k) : __shfl(z2, k - 64);

        const float logp_y   = zk - lse;
        const float sum_logp = sz - (float)NCc * lse;
        const float ce = -(0.9f * logp_y + (0.1f / (float)NCc) * sum_logp);
        if (lane == 0) csum += ce;
    }

    // ---- wave butterfly reduction of the 6 accumulators ----
    #pragma unroll
    for (int off = 32; off; off >>= 1) {
        nsum += __shfl_xor(nsum, off);
        ncnt += __shfl_xor(ncnt, off);
        bsum += __shfl_xor(bsum, off);
        osum += __shfl_xor(osum, off);
        csum += __shfl_xor(csum, off);
        ocnt += __shfl_xor(ocnt, off);
    }

    __shared__ float red[4][6];
    const int w = threadIdx.x >> 6;
    if (lane == 0) {
        red[w][0] = nsum; red[w][1] = ncnt; red[w][2] = bsum;
        red[w][3] = osum; red[w][4] = csum; red[w][5] = ocnt;
    }
    __syncthreads();
    if (threadIdx.x < 6) {
        const int j = threadIdx.x;
        partials[(size_t)blockIdx.x * 8 + j] =
            red[0][j] + red[1][j] + red[2][j] + red[3][j];
    }
}

__global__ __launch_bounds__(256) void yolo_reduce(
    const float* __restrict__ partials, float* __restrict__ out)
{
    float s[6] = {0.f, 0.f, 0.f, 0.f, 0.f, 0.f};
    for (int b = threadIdx.x; b < NBLK; b += 256) {
        #pragma unroll
        for (int j = 0; j < 6; ++j) s[j] += partials[(size_t)b * 8 + j];
    }
    #pragma unroll
    for (int off = 32; off; off >>= 1) {
        #pragma unroll
        for (int j = 0; j < 6; ++j) s[j] += __shfl_xor(s[j], off);
    }
    __shared__ float red[4][6];
    const int w = threadIdx.x >> 6, lane = threadIdx.x & 63;
    if (lane == 0) {
        #pragma unroll
        for (int j = 0; j < 6; ++j) red[w][j] = s[j];
    }
    __syncthreads();
    if (threadIdx.x == 0) {
        float n[6];
        #pragma unroll
        for (int j = 0; j < 6; ++j)
            n[j] = red[0][j] + red[1][j] + red[2][j] + red[3][j];
        const float noobj_l = n[0] / fmaxf(n[1], 1.f);
        const float box_l   = n[2] / fmaxf(n[5], 1.f);
        const float obj_l   = n[3] / fmaxf(n[5], 1.f);
        const float cls_l   = n[4] / fmaxf(n[5], 1.f);
        out[0] = 2.f * box_l + obj_l + noobj_l + cls_l;
    }
}

extern "C" void kernel_launch(void* const* d_in, const int* in_sizes, int n_in,
                              void* d_out, int out_size, void* d_ws, size_t ws_size,
                              hipStream_t stream) {
    const float* pred    = (const float*)d_in[0];
    const float* target  = (const float*)d_in[1];
    const float* anchors = (const float*)d_in[2];
    float* out = (float*)d_out;
    float* partials = (float*)d_ws;   // 2400 * 8 floats = 76.8 KB

    yolo_main<<<NBLK, BDIM, 0, stream>>>(pred, target, anchors, partials);
    yolo_reduce<<<1, 256, 0, stream>>>(partials, out);
}